// Round 1
// baseline (108.000 us; speedup 1.0000x reference)
//
#include <hip/hip_runtime.h>
#include <hip/hip_bf16.h>
#include <stdint.h>

// Batched NT-GEMM: out[b,i,j] = sum_d m1[b,i,d] * m2[b,j,d]
// B=16, M=N=2048, K=256, fp32 in/out. bf16 MFMA compute (threshold 1.89 allows it).
// Structure: learn_hip m97-verified 128x128xBK32 tile, 4 waves, 64x64/wave,
// global_load_lds width-16 staging, mfma_f32_16x16x32_bf16.

typedef __bf16 bf16x8 __attribute__((ext_vector_type(8)));
typedef __bf16 bf16x4 __attribute__((ext_vector_type(4)));
typedef float f32x4 __attribute__((ext_vector_type(4)));

#define NB    16
#define DM    2048
#define DN    2048
#define DK    256
#define BM    128
#define BN    128
#define BK    32

// ---------------- fp32 -> bf16 convert pre-pass ----------------
__global__ void cvt_kernel(const float* __restrict__ in, __bf16* __restrict__ out, int n4) {
    int i = blockIdx.x * blockDim.x + threadIdx.x;
    int stride = gridDim.x * blockDim.x;
    for (; i < n4; i += stride) {
        float4 v = reinterpret_cast<const float4*>(in)[i];
        bf16x4 o = { (__bf16)v.x, (__bf16)v.y, (__bf16)v.z, (__bf16)v.w };
        reinterpret_cast<bf16x4*>(out)[i] = o;
    }
}

// ---------------- GEMM ----------------
// PRECONV=true : A,B are bf16 (from d_ws), staged via global_load_lds (16B).
// PRECONV=false: A,B are fp32 (d_in), reg-staged with in-flight bf16 convert.
template <bool PRECONV>
__global__ __launch_bounds__(256) void gemm_bt(const void* __restrict__ Av,
                                               const void* __restrict__ Bv,
                                               float* __restrict__ C) {
    __shared__ __bf16 As[BM * BK];   // [row][k] linear, 8 KB
    __shared__ __bf16 Bs[BN * BK];   // [col][k] linear, 8 KB

    const int t    = threadIdx.x;
    const int b    = blockIdx.z;
    const int brow = blockIdx.y * BM;
    const int bcol = blockIdx.x * BN;

    const int w    = t >> 6;          // wave 0..3
    const int l    = t & 63;
    const int wr   = (w >> 1) * 64;   // wave row offset within tile
    const int wc   = (w & 1) * 64;    // wave col offset within tile
    const int lrow = l & 15;          // fragment row/col index
    const int lko  = (l >> 4) * 8;    // k-offset of this lane's 8 elements

    const f32x4 zero = {0.f, 0.f, 0.f, 0.f};
    f32x4 acc[4][4];
#pragma unroll
    for (int m = 0; m < 4; ++m)
#pragma unroll
        for (int n = 0; n < 4; ++n) acc[m][n] = zero;

#pragma unroll 1
    for (int kt = 0; kt < DK / BK; ++kt) {
        const int k0 = kt * BK;

        if constexpr (PRECONV) {
            const __bf16* At = (const __bf16*)Av + (size_t)b * DM * DK + (size_t)brow * DK;
            const __bf16* Bt = (const __bf16*)Bv + (size_t)b * DN * DK + (size_t)bcol * DK;
            // A tile = 128x32 bf16 = 8192 B = 512 chunks of 16 B; 2 chunks/thread.
            // LDS dest is linear (chunk c -> byte c*16): wave-uniform base + lane*16. 
#pragma unroll
            for (int i = 0; i < 2; ++i) {
                int c = t + i * 256;
                int r = c >> 2, q = c & 3;
                __builtin_amdgcn_global_load_lds(
                    (const __attribute__((address_space(1))) void*)(At + (size_t)r * DK + k0 + q * 8),
                    (__attribute__((address_space(3))) void*)(As + c * 8), 16, 0, 0);
                __builtin_amdgcn_global_load_lds(
                    (const __attribute__((address_space(1))) void*)(Bt + (size_t)r * DK + k0 + q * 8),
                    (__attribute__((address_space(3))) void*)(Bs + c * 8), 16, 0, 0);
            }
        } else {
            const float* At = (const float*)Av + (size_t)b * DM * DK + (size_t)brow * DK;
            const float* Bt = (const float*)Bv + (size_t)b * DN * DK + (size_t)bcol * DK;
            // A tile = 128x32 fp32 = 16 KB = 1024 float4-chunks of 16 B; 4/thread.
            // ds_write_b64 at byte c*8 -> contiguous per wave (conflict-free).
#pragma unroll
            for (int i = 0; i < 4; ++i) {
                int c = t + i * 256;
                int r = c >> 3, q = c & 7;
                float4 va = *reinterpret_cast<const float4*>(At + (size_t)r * DK + k0 + q * 4);
                float4 vb = *reinterpret_cast<const float4*>(Bt + (size_t)r * DK + k0 + q * 4);
                bf16x4 ha = { (__bf16)va.x, (__bf16)va.y, (__bf16)va.z, (__bf16)va.w };
                bf16x4 hb = { (__bf16)vb.x, (__bf16)vb.y, (__bf16)vb.z, (__bf16)vb.w };
                *reinterpret_cast<bf16x4*>(&As[r * BK + q * 4]) = ha;
                *reinterpret_cast<bf16x4*>(&Bs[r * BK + q * 4]) = hb;
            }
        }

        __syncthreads();   // compiler emits s_waitcnt vmcnt(0) lgkmcnt(0) before s_barrier

        bf16x8 af[4], bfr[4];
#pragma unroll
        for (int m = 0; m < 4; ++m)
            af[m] = *reinterpret_cast<const bf16x8*>(&As[(wr + m * 16 + lrow) * BK + lko]);
#pragma unroll
        for (int n = 0; n < 4; ++n)
            bfr[n] = *reinterpret_cast<const bf16x8*>(&Bs[(wc + n * 16 + lrow) * BK + lko]);
#pragma unroll
        for (int m = 0; m < 4; ++m)
#pragma unroll
            for (int n = 0; n < 4; ++n)
                acc[m][n] = __builtin_amdgcn_mfma_f32_16x16x32_bf16(af[m], bfr[n], acc[m][n], 0, 0, 0);

        __syncthreads();   // before next iteration overwrites LDS
    }

    // Epilogue. C/D layout (verified m89/m91): col = lane&15, row = (lane>>4)*4 + reg.
    float* Cb = C + (size_t)b * DM * DN;
    const int crow = brow + wr + (l >> 4) * 4;
    const int ccol = bcol + wc + lrow;
#pragma unroll
    for (int m = 0; m < 4; ++m)
#pragma unroll
        for (int j = 0; j < 4; ++j) {
            float* rowp = Cb + (size_t)(crow + m * 16 + j) * DN + ccol;
#pragma unroll
            for (int n = 0; n < 4; ++n)
                rowp[n * 16] = acc[m][n][j];
        }
}

extern "C" void kernel_launch(void* const* d_in, const int* in_sizes, int n_in,
                              void* d_out, int out_size, void* d_ws, size_t ws_size,
                              hipStream_t stream) {
    const float* m1 = (const float*)d_in[0];
    const float* m2 = (const float*)d_in[1];
    float* out = (float*)d_out;

    const size_t elems    = (size_t)NB * DM * DK;        // 8,388,608 per matrix
    const size_t bf_bytes = elems * sizeof(__bf16);      // 16,777,216 B

    dim3 grid(DN / BN, DM / BM, NB);   // 16 x 16 x 16 = 4096 blocks

    if (ws_size >= 2 * bf_bytes) {
        __bf16* wa = (__bf16*)d_ws;
        __bf16* wb = wa + elems;
        int n4 = (int)(elems / 4);
        cvt_kernel<<<2048, 256, 0, stream>>>(m1, wa, n4);
        cvt_kernel<<<2048, 256, 0, stream>>>(m2, wb, n4);
        gemm_bt<true><<<grid, 256, 0, stream>>>(wa, wb, out);
    } else {
        // ws too small: fused fp32->bf16 conversion inside the GEMM staging.
        gemm_bt<false><<<grid, 256, 0, stream>>>(m1, m2, out);
    }
}

// Round 2
// 81.618 us; speedup vs baseline: 1.3232x; 1.3232x over previous
//
#include <hip/hip_runtime.h>
#include <hip/hip_bf16.h>
#include <stdint.h>

// Batched NT-GEMM: out[b,i,j] = sum_d m1[b,i,d] * m2[b,j,d]
// B=16, M=N=2048, K=256, fp32 in/out; bf16 MFMA compute (absmax 0.5 vs thr 1.89).
//
// Round 2: single fused kernel.
//  - fp32 loads reg-staged, converted to bf16 in-register (no cvt pre-pass).
//  - LDS double-buffer, 1 barrier/K-step: issue next-tile loads BEFORE MFMA,
//    ds_write after (T14 async-split / minimal 2-phase).
//  - Batch-chunked XCD swizzle: each XCD walks one batch (4MB fp32 = its L2).
//  - Nontemporal C stores (write-once 256MB stream, keep panels in L2).

typedef __bf16 bf16x8 __attribute__((ext_vector_type(8)));
typedef __bf16 bf16x4 __attribute__((ext_vector_type(4)));
typedef float f32x4 __attribute__((ext_vector_type(4)));

#define NB 16
#define DM 2048
#define DN 2048
#define DK 256
#define BM 128
#define BN 128
#define BK 32
#define NT (DK / BK)          // 8 K-steps
#define NWG (NB * (DM/BM) * (DN/BN))   // 4096 blocks

__global__ __launch_bounds__(256) void fused_gemm(const float* __restrict__ A,
                                                  const float* __restrict__ B,
                                                  float* __restrict__ C) {
    __shared__ __bf16 As[2][BM * BK];   // 8 KB per buffer
    __shared__ __bf16 Bs[2][BN * BK];

    const int t = threadIdx.x;

    // XCD swizzle (NWG % 8 == 0 -> bijective). XCD k gets contiguous chunk
    // [k*512, (k+1)*512) = 2 batches; within a chunk, bx fastest (A-panel reuse).
    const int bid = blockIdx.x;
    const int swz = (bid & 7) * (NWG / 8) + (bid >> 3);
    const int b    = swz >> 8;          // 256 blocks per batch
    const int rem  = swz & 255;
    const int brow = (rem >> 4) << 7;   // * BM
    const int bcol = (rem & 15) << 7;   // * BN

    const float* At = A + (size_t)b * DM * DK + (size_t)brow * DK;
    const float* Bt = B + (size_t)b * DN * DK + (size_t)bcol * DK;

    const int w    = t >> 6;
    const int l    = t & 63;
    const int wr   = (w >> 1) * 64;     // wave row offset in tile
    const int wc   = (w & 1) * 64;      // wave col offset in tile
    const int lrow = l & 15;
    const int lko  = (l >> 4) * 8;      // k-offset of lane's 8 bf16 elements

    f32x4 acc[4][4] = {};

    // In-flight staging registers: 8 float4 = 32 VGPR.
    float4 va[4], vb[4];

    // Staging geometry: tile = 128 rows x 32 k fp32 = 1024 float4 chunks;
    // thread t owns chunks c = t + i*256 -> row r = c>>3, quad q = c&7.
    auto issue_loads = [&](int kt) {
#pragma unroll
        for (int i = 0; i < 4; ++i) {
            const int c = t + i * 256;
            const int r = c >> 3, q = c & 7;
            va[i] = *reinterpret_cast<const float4*>(At + (size_t)r * DK + kt * BK + q * 4);
            vb[i] = *reinterpret_cast<const float4*>(Bt + (size_t)r * DK + kt * BK + q * 4);
        }
    };
    auto write_lds = [&](int buf) {
#pragma unroll
        for (int i = 0; i < 4; ++i) {
            const int c = t + i * 256;
            const int r = c >> 3, q = c & 7;
            bf16x4 ha = { (__bf16)va[i].x, (__bf16)va[i].y, (__bf16)va[i].z, (__bf16)va[i].w };
            bf16x4 hb = { (__bf16)vb[i].x, (__bf16)vb[i].y, (__bf16)vb[i].z, (__bf16)vb[i].w };
            *reinterpret_cast<bf16x4*>(&As[buf][r * BK + q * 4]) = ha;
            *reinterpret_cast<bf16x4*>(&Bs[buf][r * BK + q * 4]) = hb;
        }
    };

    // Prologue: stage tile 0.
    issue_loads(0);
    write_lds(0);
    __syncthreads();

    int cur = 0;
#pragma unroll 1
    for (int kt = 0; kt < NT; ++kt) {
        // Issue next tile's global loads first -> latency hides under MFMA.
        if (kt + 1 < NT) issue_loads(kt + 1);

        bf16x8 af[4], bfr[4];
#pragma unroll
        for (int m = 0; m < 4; ++m)
            af[m] = *reinterpret_cast<const bf16x8*>(&As[cur][(wr + m * 16 + lrow) * BK + lko]);
#pragma unroll
        for (int n = 0; n < 4; ++n)
            bfr[n] = *reinterpret_cast<const bf16x8*>(&Bs[cur][(wc + n * 16 + lrow) * BK + lko]);
#pragma unroll
        for (int m = 0; m < 4; ++m)
#pragma unroll
            for (int n = 0; n < 4; ++n)
                acc[m][n] = __builtin_amdgcn_mfma_f32_16x16x32_bf16(af[m], bfr[n], acc[m][n], 0, 0, 0);

        // Write next tile into the other buffer. The barrier at the END of the
        // PREVIOUS iteration guaranteed all waves finished reading buf[cur^1],
        // so no pre-write barrier is needed; one barrier per K-step total.
        if (kt + 1 < NT) write_lds(cur ^ 1);
        __syncthreads();
        cur ^= 1;
    }

    // Epilogue. C/D layout (m89/m91): col = lane&15, row = (lane>>4)*4 + reg.
    float* Cb = C + (size_t)b * DM * DN;
    const int crow = brow + wr + (l >> 4) * 4;
    const int ccol = bcol + wc + lrow;
#pragma unroll
    for (int m = 0; m < 4; ++m)
#pragma unroll
        for (int j = 0; j < 4; ++j) {
            float* rowp = Cb + (size_t)(crow + m * 16 + j) * DN + ccol;
#pragma unroll
            for (int n = 0; n < 4; ++n)
                __builtin_nontemporal_store(acc[m][n][j], rowp + n * 16);
        }
}

extern "C" void kernel_launch(void* const* d_in, const int* in_sizes, int n_in,
                              void* d_out, int out_size, void* d_ws, size_t ws_size,
                              hipStream_t stream) {
    const float* m1 = (const float*)d_in[0];
    const float* m2 = (const float*)d_in[1];
    float* out = (float*)d_out;
    (void)d_ws; (void)ws_size;

    fused_gemm<<<NWG, 256, 0, stream>>>(m1, m2, out);
}

// Round 3
// 77.140 us; speedup vs baseline: 1.4001x; 1.0580x over previous
//
#include <hip/hip_runtime.h>
#include <hip/hip_bf16.h>
#include <stdint.h>

// Batched NT-GEMM: out[b,i,j] = sum_d m1[b,i,d] * m2[b,j,d]
// B=16, M=N=2048, K=256, fp32 in/out; bf16 MFMA compute (absmax 0.5 vs thr 1.89).
//
// Round 3: 2-deep register prefetch (named X/Y sets, statically unrolled x2).
//  - ds_write of tile k+1 uses regs issued TWO compute phases earlier ->
//    dependency-driven counted vmcnt (8 newer loads in flight), latency covered.
//  - Everything else unchanged from round 2 (XCD swizzle, 1 barrier/step,
//    fused fp32->bf16 convert, NT stores).

typedef __bf16 bf16x8 __attribute__((ext_vector_type(8)));
typedef __bf16 bf16x4 __attribute__((ext_vector_type(4)));
typedef float f32x4 __attribute__((ext_vector_type(4)));

#define NB 16
#define DM 2048
#define DN 2048
#define DK 256
#define BM 128
#define BN 128
#define BK 32
#define NT (DK / BK)                   // 8 K-steps
#define NWG (NB * (DM/BM) * (DN/BN))   // 4096 blocks

__global__ __launch_bounds__(256, 2) void fused_gemm(const float* __restrict__ A,
                                                     const float* __restrict__ B,
                                                     float* __restrict__ C) {
    __shared__ __bf16 As[2][BM * BK];   // 8 KB per buffer
    __shared__ __bf16 Bs[2][BN * BK];

    const int t = threadIdx.x;

    // XCD swizzle (NWG % 8 == 0 -> bijective). XCD k gets a contiguous chunk;
    // within a chunk bx is fastest (A-panel reuse, per-batch 4MB ~ one L2).
    const int bid = blockIdx.x;
    const int swz = (bid & 7) * (NWG / 8) + (bid >> 3);
    const int b    = swz >> 8;          // 256 blocks per batch
    const int rem  = swz & 255;
    const int brow = (rem >> 4) << 7;   // * BM
    const int bcol = (rem & 15) << 7;   // * BN

    const float* At = A + (size_t)b * DM * DK + (size_t)brow * DK;
    const float* Bt = B + (size_t)b * DN * DK + (size_t)bcol * DK;

    const int w    = t >> 6;
    const int l    = t & 63;
    const int wr   = (w >> 1) * 64;     // wave row offset in tile
    const int wc   = (w & 1) * 64;      // wave col offset in tile
    const int lrow = l & 15;
    const int lko  = (l >> 4) * 8;      // k-offset of lane's 8 bf16 elements

    f32x4 acc[4][4] = {};

    // Staging geometry: tile = 128 rows x 32 k fp32 = 1024 float4 chunks;
    // thread t owns chunks c = t + i*256 -> row r = c>>3, quad q = c&7.
    auto issue = [&](int kt, float4 (&va)[4], float4 (&vb)[4]) {
#pragma unroll
        for (int i = 0; i < 4; ++i) {
            const int c = t + i * 256;
            const int r = c >> 3, q = c & 7;
            va[i] = *reinterpret_cast<const float4*>(At + (size_t)r * DK + kt * BK + q * 4);
            vb[i] = *reinterpret_cast<const float4*>(Bt + (size_t)r * DK + kt * BK + q * 4);
        }
    };
    auto wlds = [&](int buf, const float4 (&va)[4], const float4 (&vb)[4]) {
#pragma unroll
        for (int i = 0; i < 4; ++i) {
            const int c = t + i * 256;
            const int r = c >> 3, q = c & 7;
            bf16x4 ha = { (__bf16)va[i].x, (__bf16)va[i].y, (__bf16)va[i].z, (__bf16)va[i].w };
            bf16x4 hb = { (__bf16)vb[i].x, (__bf16)vb[i].y, (__bf16)vb[i].z, (__bf16)vb[i].w };
            *reinterpret_cast<bf16x4*>(&As[buf][r * BK + q * 4]) = ha;
            *reinterpret_cast<bf16x4*>(&Bs[buf][r * BK + q * 4]) = hb;
        }
    };
    auto compute = [&](int buf) {
        bf16x8 af[4], bfr[4];
#pragma unroll
        for (int m = 0; m < 4; ++m)
            af[m] = *reinterpret_cast<const bf16x8*>(&As[buf][(wr + m * 16 + lrow) * BK + lko]);
#pragma unroll
        for (int n = 0; n < 4; ++n)
            bfr[n] = *reinterpret_cast<const bf16x8*>(&Bs[buf][(wc + n * 16 + lrow) * BK + lko]);
#pragma unroll
        for (int m = 0; m < 4; ++m)
#pragma unroll
            for (int n = 0; n < 4; ++n)
                acc[m][n] = __builtin_amdgcn_mfma_f32_16x16x32_bf16(af[m], bfr[n], acc[m][n], 0, 0, 0);
    };

    // Two named in-flight register sets (static indexing only - no runtime idx).
    float4 vaX[4], vbX[4], vaY[4], vbY[4];

    // Prologue: tiles 0 (X) and 1 (Y) in flight; write tile 0 -> buf0.
    issue(0, vaX, vbX);
    issue(1, vaY, vbY);
    wlds(0, vaX, vbX);        // counted wait: Y's 8 loads stay outstanding
    __syncthreads();

    // Steady state, manually unrolled x2 (roles X/Y alternate; buf = kt&1).
    // Even kt: issue(kt+2)->X, compute buf0, write Y(tile kt+1)->buf1.
    // Odd  kt: issue(kt+2)->Y, compute buf1, write X(tile kt+1)->buf0.
#pragma unroll
    for (int k2 = 0; k2 < NT; k2 += 2) {
        if (k2 + 2 < NT) issue(k2 + 2, vaX, vbX);
        compute(0);
        wlds(1, vaY, vbY);                 // tile k2+1 (always exists: NT even)
        __syncthreads();

        if (k2 + 3 < NT) issue(k2 + 3, vaY, vbY);
        compute(1);
        if (k2 + 2 < NT) {
            wlds(0, vaX, vbX);             // tile k2+2
        }
        __syncthreads();
    }

    // Epilogue. C/D layout (m89/m91): col = lane&15, row = (lane>>4)*4 + reg.
    float* Cb = C + (size_t)b * DM * DN;
    const int crow = brow + wr + (l >> 4) * 4;
    const int ccol = bcol + wc + lrow;
#pragma unroll
    for (int m = 0; m < 4; ++m)
#pragma unroll
        for (int j = 0; j < 4; ++j) {
            float* rowp = Cb + (size_t)(crow + m * 16 + j) * DN + ccol;
#pragma unroll
            for (int n = 0; n < 4; ++n)
                __builtin_nontemporal_store(acc[m][n][j], rowp + n * 16);
        }
}

extern "C" void kernel_launch(void* const* d_in, const int* in_sizes, int n_in,
                              void* d_out, int out_size, void* d_ws, size_t ws_size,
                              hipStream_t stream) {
    const float* m1 = (const float*)d_in[0];
    const float* m2 = (const float*)d_in[1];
    float* out = (float*)d_out;
    (void)d_ws; (void)ws_size;

    fused_gemm<<<NWG, 256, 0, stream>>>(m1, m2, out);
}

// Round 5
// 75.769 us; speedup vs baseline: 1.4254x; 1.0181x over previous
//
#include <hip/hip_runtime.h>
#include <hip/hip_bf16.h>
#include <stdint.h>

// Batched NT-GEMM: out[b,i,j] = sum_d m1[b,i,d] * m2[b,j,d]
// B=16, M=N=2048, K=256, fp32 in/out; f16 MFMA compute (N(0,1) inputs, thr 1.89).
//
// Round 5 = round 4 with the cvt_pkrtz type mismatch fixed via bit_cast.
//  - LDS row stride padded 32 -> 36 elems (72B): frag ds_read_b128 banks become
//    (row*18 + hi*4) % 32 -> all 16 rows distinct, ~2-way max (free, m136).
//    Was 64B stride -> 4-8-way conflicts (m98: 1.7e7 SQ_LDS_BANK_CONFLICT).
//  - fp32->f16 via v_cvt_pkrtz_f16_f32 (1 instr / 2 floats, guaranteed) +
//    mfma_f32_16x16x32_f16 (same rate as bf16, m64). Better mantissa too.

typedef _Float16 f16x8 __attribute__((ext_vector_type(8)));
typedef _Float16 f16x4 __attribute__((ext_vector_type(4)));
typedef _Float16 f16x2 __attribute__((ext_vector_type(2)));
typedef float f32x4 __attribute__((ext_vector_type(4)));

#define NB 16
#define DM 2048
#define DN 2048
#define DK 256
#define BM 128
#define BN 128
#define BK 32
#define BKP 36                          // padded LDS row stride (elements)
#define NT (DK / BK)                    // 8 K-steps
#define NWG (NB * (DM/BM) * (DN/BN))    // 4096 blocks

__global__ __launch_bounds__(256, 2) void fused_gemm(const float* __restrict__ A,
                                                     const float* __restrict__ B,
                                                     float* __restrict__ C) {
    __shared__ _Float16 As[2][BM * BKP];   // 9216 B per buffer
    __shared__ _Float16 Bs[2][BN * BKP];

    const int t = threadIdx.x;

    // XCD swizzle (NWG % 8 == 0 -> bijective). XCD k gets a contiguous chunk;
    // within a chunk bx is fastest (per-batch panels ~4MB ~ one XCD L2).
    const int bid = blockIdx.x;
    const int swz = (bid & 7) * (NWG / 8) + (bid >> 3);
    const int b    = swz >> 8;          // 256 blocks per batch
    const int rem  = swz & 255;
    const int brow = (rem >> 4) << 7;   // * BM
    const int bcol = (rem & 15) << 7;   // * BN

    const float* At = A + (size_t)b * DM * DK + (size_t)brow * DK;
    const float* Bt = B + (size_t)b * DN * DK + (size_t)bcol * DK;

    const int w    = t >> 6;
    const int l    = t & 63;
    const int wr   = (w >> 1) * 64;     // wave row offset in tile
    const int wc   = (w & 1) * 64;      // wave col offset in tile
    const int lrow = l & 15;
    const int lko  = (l >> 4) * 8;      // k-offset of lane's 8 f16 elements

    f32x4 acc[4][4] = {};

    // Staging geometry: tile = 128 rows x 32 k fp32 = 1024 float4 chunks;
    // thread t owns chunks c = t + i*256 -> row r = c>>3, quad q = c&7.
    auto issue = [&](int kt, float4 (&va)[4], float4 (&vb)[4]) {
#pragma unroll
        for (int i = 0; i < 4; ++i) {
            const int c = t + i * 256;
            const int r = c >> 3, q = c & 7;
            va[i] = *reinterpret_cast<const float4*>(At + (size_t)r * DK + kt * BK + q * 4);
            vb[i] = *reinterpret_cast<const float4*>(Bt + (size_t)r * DK + kt * BK + q * 4);
        }
    };
    auto wlds = [&](int buf, const float4 (&va)[4], const float4 (&vb)[4]) {
#pragma unroll
        for (int i = 0; i < 4; ++i) {
            const int c = t + i * 256;
            const int r = c >> 3, q = c & 7;
            f16x2 alo = __builtin_bit_cast(f16x2, __builtin_amdgcn_cvt_pkrtz(va[i].x, va[i].y));
            f16x2 ahi = __builtin_bit_cast(f16x2, __builtin_amdgcn_cvt_pkrtz(va[i].z, va[i].w));
            f16x2 blo = __builtin_bit_cast(f16x2, __builtin_amdgcn_cvt_pkrtz(vb[i].x, vb[i].y));
            f16x2 bhi = __builtin_bit_cast(f16x2, __builtin_amdgcn_cvt_pkrtz(vb[i].z, vb[i].w));
            f16x4 ha = { alo[0], alo[1], ahi[0], ahi[1] };
            f16x4 hb = { blo[0], blo[1], bhi[0], bhi[1] };
            *reinterpret_cast<f16x4*>(&As[buf][r * BKP + q * 4]) = ha;
            *reinterpret_cast<f16x4*>(&Bs[buf][r * BKP + q * 4]) = hb;
        }
    };
    auto compute = [&](int buf) {
        f16x8 af[4], bfr[4];
#pragma unroll
        for (int m = 0; m < 4; ++m)
            af[m] = *reinterpret_cast<const f16x8*>(&As[buf][(wr + m * 16 + lrow) * BKP + lko]);
#pragma unroll
        for (int n = 0; n < 4; ++n)
            bfr[n] = *reinterpret_cast<const f16x8*>(&Bs[buf][(wc + n * 16 + lrow) * BKP + lko]);
#pragma unroll
        for (int m = 0; m < 4; ++m)
#pragma unroll
            for (int n = 0; n < 4; ++n)
                acc[m][n] = __builtin_amdgcn_mfma_f32_16x16x32_f16(af[m], bfr[n], acc[m][n], 0, 0, 0);
    };

    // Two named in-flight register sets (static indexing only - rule #20).
    float4 vaX[4], vbX[4], vaY[4], vbY[4];

    // Prologue: tiles 0 (X) and 1 (Y) in flight; write tile 0 -> buf0.
    issue(0, vaX, vbX);
    issue(1, vaY, vbY);
    wlds(0, vaX, vbX);        // counted wait: Y's 8 loads stay outstanding
    __syncthreads();

    // Steady state, manually unrolled x2 (roles X/Y alternate; buf = kt&1).
#pragma unroll
    for (int k2 = 0; k2 < NT; k2 += 2) {
        if (k2 + 2 < NT) issue(k2 + 2, vaX, vbX);
        compute(0);
        wlds(1, vaY, vbY);                 // tile k2+1 (NT even -> exists)
        __syncthreads();

        if (k2 + 3 < NT) issue(k2 + 3, vaY, vbY);
        compute(1);
        if (k2 + 2 < NT) {
            wlds(0, vaX, vbX);             // tile k2+2
        }
        __syncthreads();
    }

    // Epilogue. C/D layout (m89/m91): col = lane&15, row = (lane>>4)*4 + reg.
    float* Cb = C + (size_t)b * DM * DN;
    const int crow = brow + wr + (l >> 4) * 4;
    const int ccol = bcol + wc + lrow;
#pragma unroll
    for (int m = 0; m < 4; ++m)
#pragma unroll
        for (int j = 0; j < 4; ++j) {
            float* rowp = Cb + (size_t)(crow + m * 16 + j) * DN + ccol;
#pragma unroll
            for (int n = 0; n < 4; ++n)
                __builtin_nontemporal_store(acc[m][n][j], rowp + n * 16);
        }
}

extern "C" void kernel_launch(void* const* d_in, const int* in_sizes, int n_in,
                              void* d_out, int out_size, void* d_ws, size_t ws_size,
                              hipStream_t stream) {
    const float* m1 = (const float*)d_in[0];
    const float* m2 = (const float*)d_in[1];
    float* out = (float*)d_out;
    (void)d_ws; (void)ws_size;

    fused_gemm<<<NWG, 256, 0, stream>>>(m1, m2, out);
}